// Round 5
// baseline (275.481 us; speedup 1.0000x reference)
//
#include <hip/hip_runtime.h>
#include <math.h>

// B=2048 rows, L=16384, W=30 sliding mean of sigmoid(x)*mask, per-row max.
// R5 (= R4 fixed): wave-autonomous LDS-free streaming. Each wave owns a
// 4096-elem row segment, streamed in 256-elem chunks (float4/lane). Window
// sums via within-chunk prefix sums: per-lane prefix + DPP wave scan +
// ds_bpermute for the (j-30) subtrahend (7-8 lanes back). No barriers, no
// LDS tiles, no vmcnt(0) drains -> continuous load issue (m13-copy regime).
constexpr int Bn    = 2048;
constexpr int L     = 16384;
constexpr int W     = 30;
constexpr int NSEG  = 4;              // waves per row (one block of 256)
constexpr int SEG   = L / NSEG;       // 4096 elements per wave
constexpr int CHUNK = 256;            // 64 lanes x float4
constexpr int NCH   = SEG / CHUNK;    // 16 chunks per wave

template <int CTRL, int RMASK>
__device__ __forceinline__ float dpp_add(float x) {
    // old = 0: shifted-in / masked lanes contribute 0.0f
    int s = __builtin_amdgcn_update_dpp(0, __float_as_int(x), CTRL, RMASK, 0xf, false);
    return x + __int_as_float(s);
}

// wave64 inclusive +scan (rocPRIM-style DPP sequence)
__device__ __forceinline__ float wave_iscan(float x) {
    x = dpp_add<0x111, 0xf>(x);   // row_shr:1
    x = dpp_add<0x112, 0xf>(x);   // row_shr:2
    x = dpp_add<0x114, 0xf>(x);   // row_shr:4
    x = dpp_add<0x118, 0xf>(x);   // row_shr:8
    x = dpp_add<0x142, 0xa>(x);   // row_bcast:15 -> rows 1,3
    x = dpp_add<0x143, 0xc>(x);   // row_bcast:31 -> rows 2,3
    return x;
}

__device__ __forceinline__ float bperm(int byteaddr, float v) {
    return __int_as_float(__builtin_amdgcn_ds_bpermute(byteaddr, __float_as_int(v)));
}

__device__ __forceinline__ float sigp(float xv, float mv) {
    // m / (1 + 2^(-x*log2 e)): mul, exp(trans), add, rcp(trans), mul
    return mv * __builtin_amdgcn_rcpf(1.0f + __builtin_amdgcn_exp2f(-1.44269504089f * xv));
}

// Within-chunk inclusive prefix at this lane's 4 positions (4l..4l+3).
__device__ __forceinline__ void chunk_prefix(float4 xv, float4 mv,
                                             float& u0, float& u1, float& u2, float& u3) {
    float p0 = sigp(xv.x, mv.x);
    float p1 = sigp(xv.y, mv.y);
    float p2 = sigp(xv.z, mv.z);
    float p3 = sigp(xv.w, mv.w);
    float T  = (p0 + p1) + (p2 + p3);
    float inc = wave_iscan(T);        // inclusive scan of lane totals
    u3 = inc;                         // = exclusive + T
    u2 = inc - p3;
    u1 = u2 - p2;
    u0 = u1 - p1;
}

__global__ __launch_bounds__(256, 8)
void winmax_stream(const float* __restrict__ x,
                   const float* __restrict__ m,
                   float* __restrict__ out) {
    const int row  = blockIdx.x;
    const int seg  = threadIdx.x >> 6;
    const int lane = threadIdx.x & 63;

    const float4* x4 = (const float4*)x + (size_t)row * (L / 4) + seg * (SEG / 4) + lane;
    const float4* m4 = (const float4*)m + (size_t)row * (L / 4) + seg * (SEG / 4) + lane;

    // Subtrahend source lanes: window ending at 4l+c needs prefix at (4l+c-30):
    // c=0,1 -> lane l-8 elems 2,3 ; c=2,3 -> lane l-7 elems 0,1. Lanes whose
    // source wraps (l<8 / l<7) read prev-chunk values published by high lanes.
    const int  a8 = ((lane - 8) & 63) << 2;
    const int  a7 = ((lane - 7) & 63) << 2;
    const bool c8 = (lane >= 56);     // this lane serves a wrapped request
    const bool c7 = (lane >= 57);

    // Warmup: previous 256 elements (covers the 29-elem window history).
    // seg==0: zeros = reference's prefix zero-pad; truncated early windows
    // are subsets of the valid window ending at 29 (all terms >=0) -> never win.
    float pu0 = 0.f, pu1 = 0.f, pu2 = 0.f, pu3 = 0.f, D = 0.f;
    if (seg > 0) {
        float4 wx = x4[-64], wm = m4[-64];
        chunk_prefix(wx, wm, pu0, pu1, pu2, pu3);
        D = bperm(63 << 2, pu3);      // prev-chunk total (uniform)
    }

    float best = 0.0f;
    float4 cx = x4[0], cm = m4[0];
    #pragma unroll 4
    for (int k = 0; k < NCH; ++k) {
        float4 nx, nm;
        if (k + 1 < NCH) { nx = x4[(k + 1) * 64]; nm = m4[(k + 1) * 64]; }  // prefetch

        float u0, u1, u2, u3;
        chunk_prefix(cx, cm, u0, u1, u2, u3);
        float tot = bperm(63 << 2, u3);

        // Publishers: high lanes serve cross-chunk requests with prev-chunk
        // prefix rebased by -D (S = PP(j) - (PPprev(jsub) - D)).
        float s8a = c8 ? (pu2 - D) : u2;
        float s8b = c8 ? (pu3 - D) : u3;
        float s7a = c7 ? (pu0 - D) : u0;
        float s7b = c7 ? (pu1 - D) : u1;
        float x0 = bperm(a8, s8a);
        float x1 = bperm(a8, s8b);
        float x2 = bperm(a7, s7a);
        float x3 = bperm(a7, s7b);

        float S0 = u0 - x0, S1 = u1 - x1, S2 = u2 - x2, S3 = u3 - x3;
        best = fmaxf(best, fmaxf(fmaxf(S0, S1), fmaxf(S2, S3)));

        pu0 = u0; pu1 = u1; pu2 = u2; pu3 = u3; D = tot;
        cx = nx; cm = nm;
    }
    best *= (1.0f / W);

    // Wave max-reduce (butterfly), one atomic per wave.
    #pragma unroll
    for (int d = 1; d < 64; d <<= 1)
        best = fmaxf(best, __shfl_xor(best, d, 64));
    if (lane == 0)
        atomicMax((unsigned int*)(out + row), __float_as_uint(best));  // win_mean >= 0
}

extern "C" void kernel_launch(void* const* d_in, const int* in_sizes, int n_in,
                              void* d_out, int out_size, void* d_ws, size_t ws_size,
                              hipStream_t stream) {
    const float* x = (const float*)d_in[0];
    const float* m = (const float*)d_in[1];
    float* out = (float*)d_out;
    // out poisoned 0xAA (huge as uint) -> must zero for atomicMax.
    (void)hipMemsetAsync(out, 0, Bn * sizeof(float), stream);
    winmax_stream<<<Bn, 256, 0, stream>>>(x, m, out);
}